// Round 4
// baseline (105.340 us; speedup 1.0000x reference)
//
#include <hip/hip_runtime.h>
#include <math.h>

// EngineOrderFFT via batched Bluestein, fully LDS-resident per row.
// |X| = |conv[:, :K]| (final chirp is unit-modulus). M=16384 as 128x128
// four-step done inside ONE workgroup: the whole row (128 KB float2) lives
// in LDS. 16-lane register-resident 128-pt DIF/DIT cores; mid-transposes go
// through the row's own LDS slots (wave-local, no barriers) with a 2-level
// XOR swizzle keeping every pattern at the 4-way b64 floor.
//   kernel eofft_bhat : per b, build chirp -> fwd 2D FFT -> Bhat (8 MB)
//   kernel eofft_main : per (b,ch), build a -> phaseA(cols) -> phaseB(rows:
//                       fwd + *Bhat + inv + twiddle) -> phaseC(cols) -> |.|

static constexpr int Bn = 64;
static constexpr int Nn = 8192;
static constexpr int Mm = 16384;

#define PI_F 3.14159265358979323846f
#define TWO_PI_F 6.28318530717958647692f
#define R2_F 0.70710678118654752f

__device__ __forceinline__ int compute_n(float rpm) {
    // ref: pad = floor((40*60/rpm - 1)*8192) in f32; n = 8192 + pad
    return 8192 + (int)floorf((2400.0f / rpm - 1.0f) * 8192.0f);
}
__device__ __forceinline__ float2 cmul(float2 a, float2 b) {
    return make_float2(a.x*b.x - a.y*b.y, a.x*b.y + a.y*b.x);
}
__device__ __forceinline__ float2 cadd(float2 a, float2 b){ return make_float2(a.x+b.x, a.y+b.y); }
__device__ __forceinline__ float2 csub(float2 a, float2 b){ return make_float2(a.x-b.x, a.y-b.y); }
__device__ __forceinline__ float2 shflx1(float2 v) {
    return make_float2(__shfl_xor(v.x, 1, 64), __shfl_xor(v.y, 1, 64));
}

#define BF(lo,hi,tw) { float2 _d = csub(lo,hi); lo = cadd(lo,hi); hi = cmul(_d, tw); }
#define BT(lo,hi,tw) { float2 _b = cmul(hi,tw); hi = csub(lo,_b); lo = cadd(lo,_b); }
#define SELC(r,c0,s0,c1,s1) ((r) ? make_float2(c1,s1) : make_float2(c0,s0))

// element (r,c) of the 128x128 tile; XOR swizzle => all our wave64 b64
// access patterns (rows, cols, bitrev-pos rows/cols, linear) hit the
// 4-lanes-per-bank-pair minimum.
__device__ __forceinline__ int bigidx(int r, int c) {
    int sw = ((r & 15) ^ ((r >> 4) << 1) ^ ((c >> 4) << 1)) & 15;
    return (r << 7) + (c ^ sw);
}

struct ColAddr { int c; };   // sub-FFT along rows (fixed column)
struct RowAddr { int r; };   // sub-FFT along cols (fixed row)
__device__ __forceinline__ int addr_of(ColAddr a, int u) { return bigidx(u, a.c); }
__device__ __forceinline__ int addr_of(RowAddr a, int u) { return bigidx(a.r, u); }

// ---- forward 128-pt DIF, 16 lanes x 8 regs. In: v[q] = x[p+16q] (natural).
// Out: v[s] = X at bitrev-position j = 16*(p>>1)+(p&1)+2s (freq = brev7(j)).
// Mid-transpose via this sub-FFT's own LDS slots (wave-local, no barrier).
template<class AD>
__device__ __forceinline__ void dif128(float2 v[8], float2* L, AD ad, int p) {
    float sn, cs;
    __sincosf(PI_F * (float)p * (1.0f/64.0f), &sn, &cs);
    float2 w1 = make_float2(cs, -sn);          // W^-p
    float2 w2 = cmul(w1, w1);
    float2 w4 = cmul(w2, w2);
    BF(v[0],v[4], w1);
    BF(v[1],v[5], cmul(w1, make_float2(R2_F,-R2_F)));
    BF(v[2],v[6], make_float2(w1.y, -w1.x));
    BF(v[3],v[7], cmul(w1, make_float2(-R2_F,-R2_F)));
    float2 w2i = make_float2(w2.y, -w2.x);
    BF(v[0],v[2], w2);  BF(v[1],v[3], w2i);
    BF(v[4],v[6], w2);  BF(v[5],v[7], w2i);
    BF(v[0],v[1], w4);  BF(v[2],v[3], w4);
    BF(v[4],v[5], w4);  BF(v[6],v[7], w4);
    #pragma unroll
    for (int q = 0; q < 8; ++q) L[addr_of(ad, p + 16*q)] = v[q];
    int bb = p >> 1, r = p & 1;
    #pragma unroll
    for (int s = 0; s < 8; ++s) v[s] = L[addr_of(ad, 16*bb + r + 2*s)];
    BF(v[0],v[4], SELC(r, 1.f,0.f,                    0.92387953f,-0.38268343f));
    BF(v[1],v[5], SELC(r, 0.70710678f,-0.70710678f,   0.38268343f,-0.92387953f));
    BF(v[2],v[6], SELC(r, 0.f,-1.f,                  -0.38268343f,-0.92387953f));
    BF(v[3],v[7], SELC(r, -0.70710678f,-0.70710678f, -0.92387953f,-0.38268343f));
    BF(v[0],v[2], SELC(r, 1.f,0.f,  0.70710678f,-0.70710678f));
    BF(v[1],v[3], SELC(r, 0.f,-1.f, -0.70710678f,-0.70710678f));
    BF(v[4],v[6], SELC(r, 1.f,0.f,  0.70710678f,-0.70710678f));
    BF(v[5],v[7], SELC(r, 0.f,-1.f, -0.70710678f,-0.70710678f));
    #pragma unroll
    for (int s = 0; s < 8; s += 2) {
        float2 d = csub(v[s], v[s+1]);
        v[s] = cadd(v[s], v[s+1]);
        v[s+1] = r ? make_float2(d.y, -d.x) : d;
    }
    #pragma unroll
    for (int s = 0; s < 8; ++s) {
        float2 o = shflx1(v[s]);
        v[s] = r ? csub(o, v[s]) : cadd(v[s], o);
    }
}

// ---- inverse 128-pt DIT. In: v[s] = y at bitrev-pos j = 16*(p>>1)+(p&1)+2s
// (y[pos]=Y[brev7(pos)]). Out natural: v[q] = z[p+16q], unscaled +i transform.
template<class AD>
__device__ __forceinline__ void dit128(float2 v[8], float2* L, AD ad, int p) {
    int bb = p >> 1, r = p & 1;
    #pragma unroll
    for (int s = 0; s < 8; ++s) {
        float2 o = shflx1(v[s]);
        v[s] = r ? csub(o, v[s]) : cadd(v[s], o);
    }
    #pragma unroll
    for (int s = 0; s < 8; s += 2) {
        float2 b = v[s+1];
        if (r) b = make_float2(-b.y, b.x);
        v[s+1] = csub(v[s], b);
        v[s] = cadd(v[s], b);
    }
    BT(v[0],v[2], SELC(r, 1.f,0.f,  0.70710678f,0.70710678f));
    BT(v[1],v[3], SELC(r, 0.f,1.f, -0.70710678f,0.70710678f));
    BT(v[4],v[6], SELC(r, 1.f,0.f,  0.70710678f,0.70710678f));
    BT(v[5],v[7], SELC(r, 0.f,1.f, -0.70710678f,0.70710678f));
    BT(v[0],v[4], SELC(r, 1.f,0.f,                   0.92387953f,0.38268343f));
    BT(v[1],v[5], SELC(r, 0.70710678f,0.70710678f,   0.38268343f,0.92387953f));
    BT(v[2],v[6], SELC(r, 0.f,1.f,                  -0.38268343f,0.92387953f));
    BT(v[3],v[7], SELC(r, -0.70710678f,0.70710678f, -0.92387953f,0.38268343f));
    #pragma unroll
    for (int s = 0; s < 8; ++s) L[addr_of(ad, 16*bb + r + 2*s)] = v[s];
    #pragma unroll
    for (int q = 0; q < 8; ++q) v[q] = L[addr_of(ad, p + 16*q)];
    float sn, cs;
    __sincosf(PI_F * (float)p * (1.0f/64.0f), &sn, &cs);
    float2 w1 = make_float2(cs, sn);           // W^+p
    float2 w2 = cmul(w1, w1);
    float2 w4 = cmul(w2, w2);
    BT(v[0],v[1], w4); BT(v[2],v[3], w4); BT(v[4],v[5], w4); BT(v[6],v[7], w4);
    float2 w2j = make_float2(-w2.y, w2.x);
    BT(v[0],v[2], w2);  BT(v[1],v[3], w2j);
    BT(v[4],v[6], w2);  BT(v[5],v[7], w2j);
    BT(v[0],v[4], w1);
    BT(v[1],v[5], cmul(w1, make_float2(R2_F, R2_F)));
    BT(v[2],v[6], make_float2(-w1.y, w1.x));
    BT(v[3],v[7], cmul(w1, make_float2(-R2_F, R2_F)));
}

// ---------------- Bhat builder: one block per b ----------------
__global__ __launch_bounds__(1024) void eofft_bhat(const float* __restrict__ rpm,
                                                   float2* __restrict__ bhat) {
    extern __shared__ float2 L[];
    int tid = threadIdx.x;
    int f = tid >> 4, p = tid & 15;
    int b = blockIdx.x;
    int n = compute_n(rpm[b]);
    int two_n = 2 * n;
    float inv_n = 1.0f / (float)n;

    #pragma unroll
    for (int i = 0; i < 16; ++i) {
        int t = i * 1024 + tid;
        int mm = min(t, Mm - t);
        int ph = (mm * mm) % two_n;
        float sn, cs; __sincosf(PI_F * (float)ph * inv_n, &sn, &cs);
        L[bigidx(t >> 7, t & 127)] = make_float2(cs, sn);   // exp(+i b_phase)
    }
    __syncthreads();
    // phase A: columns
    #pragma unroll
    for (int c0 = 0; c0 < 128; c0 += 64) {
        int t1 = c0 + f;
        float2 v[8];
        #pragma unroll
        for (int q = 0; q < 8; ++q) v[q] = L[bigidx(p + 16*q, t1)];
        dif128(v, L, ColAddr{t1}, p);
        int bb = p >> 1, r = p & 1;
        #pragma unroll
        for (int s = 0; s < 8; ++s) {
            int j = 16*bb + r + 2*s;
            int k2 = __brev((unsigned)j) >> 25;
            float sn, cs;
            __sincosf(-TWO_PI_F * (float)(t1 * k2) * (1.0f/16384.0f), &sn, &cs);
            L[bigidx(j, t1)] = cmul(v[s], make_float2(cs, sn));
        }
    }
    __syncthreads();
    // phase B forward only -> Bhat[b][j][p*8+s]
    #pragma unroll
    for (int r0 = 0; r0 < 128; r0 += 64) {
        int j = r0 + f;
        float2 v[8];
        #pragma unroll
        for (int q = 0; q < 8; ++q) v[q] = L[bigidx(j, p + 16*q)];
        dif128(v, L, RowAddr{j}, p);
        float2* bo = bhat + ((size_t)b << 14) + (j << 7) + (p << 3);
        #pragma unroll
        for (int s = 0; s < 8; ++s) bo[s] = v[s];
    }
}

// ---------------- main: one block per (b,ch) ----------------
__global__ __launch_bounds__(1024) void eofft_main(const float* __restrict__ x,
                                                   const float* __restrict__ rpm,
                                                   const float2* __restrict__ bhat,
                                                   float* __restrict__ out) {
    extern __shared__ float2 L[];
    int tid = threadIdx.x;
    int f = tid >> 4, p = tid & 15;
    int b = blockIdx.x & 63;          // ch*64+b: channel-siblings share an XCD
    int ch = blockIdx.x >> 6;
    int n = compute_n(rpm[b]);
    int two_n = 2 * n;
    float inv_n = 1.0f / (float)n;
    const float* xb = x + ((size_t)b << 16) + ch;

    // build a = x * exp(-i a_phase), zero-pad
    #pragma unroll
    for (int i = 0; i < 16; ++i) {
        int t = i * 1024 + tid;
        float2 val = make_float2(0.f, 0.f);
        if (t < Nn) {
            float xv = xb[(size_t)t << 3];
            int ph = (t * t) % two_n;
            float sn, cs; __sincosf(PI_F * (float)ph * inv_n, &sn, &cs);
            val = make_float2(xv * cs, -xv * sn);
        }
        L[bigidx(t >> 7, t & 127)] = val;
    }
    __syncthreads();
    // phase A: fwd FFT over t2 per column t1, * W^{-t1*k2}, store at bitrev row
    #pragma unroll
    for (int c0 = 0; c0 < 128; c0 += 64) {
        int t1 = c0 + f;
        float2 v[8];
        #pragma unroll
        for (int q = 0; q < 8; ++q) v[q] = L[bigidx(p + 16*q, t1)];
        dif128(v, L, ColAddr{t1}, p);
        int bb = p >> 1, r = p & 1;
        #pragma unroll
        for (int s = 0; s < 8; ++s) {
            int j = 16*bb + r + 2*s;
            int k2 = __brev((unsigned)j) >> 25;
            float sn, cs;
            __sincosf(-TWO_PI_F * (float)(t1 * k2) * (1.0f/16384.0f), &sn, &cs);
            L[bigidx(j, t1)] = cmul(v[s], make_float2(cs, sn));
        }
    }
    __syncthreads();
    // phase B per row j (k2=brev(j)): fwd FFT over t1 -> *Bhat -> inv FFT over
    // k1 -> * e^{+2pi i k2 t1 / M} -> back in place (natural t1)
    #pragma unroll
    for (int r0 = 0; r0 < 128; r0 += 64) {
        int j = r0 + f;
        int k2 = __brev((unsigned)j) >> 25;
        float2 v[8];
        #pragma unroll
        for (int q = 0; q < 8; ++q) v[q] = L[bigidx(j, p + 16*q)];
        dif128(v, L, RowAddr{j}, p);
        const float2* bh = bhat + ((size_t)b << 14) + (j << 7) + (p << 3);
        #pragma unroll
        for (int s = 0; s < 8; ++s) v[s] = cmul(v[s], bh[s]);
        dit128(v, L, RowAddr{j}, p);
        #pragma unroll
        for (int q = 0; q < 8; ++q) {
            int t1 = p + 16*q;
            float sn, cs;
            __sincosf(TWO_PI_F * (float)(k2 * t1) * (1.0f/16384.0f), &sn, &cs);
            L[bigidx(j, t1)] = cmul(v[q], make_float2(cs, sn));
        }
    }
    __syncthreads();
    // phase C: inverse FFT over k2 per column t1 (rows already bitrev-placed),
    // keep m = t1 + 128*t2 < 8192, write |.|/M
    #pragma unroll
    for (int c0 = 0; c0 < 128; c0 += 64) {
        int t1 = c0 + f;
        float2 v[8];
        int bb = p >> 1, r = p & 1;
        #pragma unroll
        for (int s = 0; s < 8; ++s) v[s] = L[bigidx(16*bb + r + 2*s, t1)];
        dit128(v, L, ColAddr{t1}, p);
        float* ob = out + (((size_t)(b << 13) + t1) << 3) + ch;
        #pragma unroll
        for (int q = 0; q < 4; ++q) {
            int t2 = p + 16*q;
            float2 z = v[q];
            ob[(size_t)t2 << 10] = sqrtf(z.x*z.x + z.y*z.y) * (1.0f/16384.0f);
        }
    }
}

// ---------------- launch ----------------
extern "C" void kernel_launch(void* const* d_in, const int* in_sizes, int n_in,
                              void* d_out, int out_size, void* d_ws, size_t ws_size,
                              hipStream_t stream) {
    const float* x   = (const float*)d_in[0];
    const float* rpm = (const float*)d_in[1];
    float* outF = (float*)d_out;
    float2* bhat = (float2*)d_ws;                    // 64*16384 float2 = 8 MiB

    eofft_bhat<<<Bn, 1024, 131072, stream>>>(rpm, bhat);
    eofft_main<<<Bn * 8, 1024, 131072, stream>>>(x, rpm, bhat, outF);
}